// Round 12
// baseline (420.077 us; speedup 1.0000x reference)
//
#include <hip/hip_runtime.h>

// Luong 'general' attention, B=4 D=256 L=4096.
// K0 transpose/cast q,c -> [B][L][D] f16 (+ fused cD16 [B][D][L] f16 cast);
// K0b W f32->f16 ; K1 linear qw=q@W^T+b.
// K2 attn_main: 256 blocks lockstep, 512 thr = 8 waves (2/SIMD -> 256 VGPR cap).
//   TQ=128, 32 iterations/phase (r9/r10 showed cost ~ per-iteration, not traffic).
//   Scores: wave qs (0..7) owns one q-frag x ALL 64 o (qb[4][8], 128 VGPR,
//   zero A-read redundancy). PV: wave (dw 0..3, kh 0..1), oacc[4][4].
//   phase A: staged scores, lsum += exp(s); phase B: recompute (bit-identical),
//   w=exp(s)*invl -> f32x4 wgt + f16x4 wbuf; PV A=wbuf b128, B from L2-hot cD16.
// LDS: 2x64KB c_lds + 16KB wbuf + 2KB redbuf = 146 KB (obuf aliases smem[0]).

#define BATCH 4
#define DDIM  256
#define LSEQ  4096
#define TQ    128

typedef float    f32x4 __attribute__((ext_vector_type(4)));
typedef _Float16 f16x8 __attribute__((ext_vector_type(8)));
typedef _Float16 f16x4 __attribute__((ext_vector_type(4)));

__device__ __forceinline__ void gld16(const void* g, void* l) {
  __builtin_amdgcn_global_load_lds((const __attribute__((address_space(1))) void*)g,
                                   (__attribute__((address_space(3))) void*)l, 16, 0, 0);
}

// ---------------- K0: [B][D][L] f32 -> [B][L][D] f16 (+ cD16 for context) ---
__global__ __launch_bounds__(256) void transpose_cast(
    const float* __restrict__ q_in, const float* __restrict__ c_in,
    _Float16* __restrict__ q_out, _Float16* __restrict__ c_out,
    _Float16* __restrict__ cD16)
{
  __shared__ float tile[64][68];
  const int which = blockIdx.z >> 2;
  const int b     = blockIdx.z & 3;
  const float* __restrict__ src = which ? c_in : q_in;
  _Float16* __restrict__ dst    = which ? c_out : q_out;
  const int l0 = blockIdx.x * 64, d0 = blockIdx.y * 64;
  const int tid = threadIdx.x;
  const int tr = tid >> 4, tc = (tid & 15) << 2;
#pragma unroll
  for (int i = 0; i < 4; ++i) {
    int d = tr + i * 16;
    f32x4 v = *(const f32x4*)(src + ((size_t)b * DDIM + d0 + d) * LSEQ + l0 + tc);
    *(f32x4*)&tile[d][tc] = v;
    if (which) {
      f16x4 h;
      h[0] = (_Float16)v[0]; h[1] = (_Float16)v[1];
      h[2] = (_Float16)v[2]; h[3] = (_Float16)v[3];
      *(f16x4*)(cD16 + ((size_t)b * DDIM + d0 + d) * LSEQ + l0 + tc) = h;
    }
  }
  __syncthreads();
#pragma unroll
  for (int i = 0; i < 4; ++i) {
    int l = tr + i * 16;
    f16x4 h;
    h[0] = (_Float16)tile[tc + 0][l];
    h[1] = (_Float16)tile[tc + 1][l];
    h[2] = (_Float16)tile[tc + 2][l];
    h[3] = (_Float16)tile[tc + 3][l];
    *(f16x4*)(dst + ((size_t)b * LSEQ + l0 + l) * DDIM + d0 + tc) = h;
  }
}

// ---------------- K0b: W f32 -> f16 -----------------------------------------
__global__ __launch_bounds__(256) void wconv(const float* __restrict__ w,
                                             _Float16* __restrict__ w16) {
  int i = (blockIdx.x * 256 + threadIdx.x) * 4;
  f32x4 v = *(const f32x4*)(w + i);
  f16x4 h;
  h[0] = (_Float16)v[0]; h[1] = (_Float16)v[1];
  h[2] = (_Float16)v[2]; h[3] = (_Float16)v[3];
  *(f16x4*)(w16 + i) = h;
}

// ---------------- K1: qw16 = qT16 @ W^T + bias ------------------------------
__global__ __launch_bounds__(256) void linear_q(
    const _Float16* __restrict__ qT16, const _Float16* __restrict__ W16,
    const float* __restrict__ bias, _Float16* __restrict__ qw16)
{
  const int tid = threadIdx.x;
  const int wv = tid >> 6, ln = tid & 63, g = ln >> 4, c16 = ln & 15;
  const size_t r0 = (size_t)blockIdx.x * 64 + wv * 16;

  f16x8 qa[8];
  const _Float16* qrow = qT16 + (r0 + c16) * DDIM + g * 8;
#pragma unroll
  for (int kk = 0; kk < 8; ++kk) qa[kk] = *(const f16x8*)(qrow + kk * 32);

  f32x4 acc[16];
#pragma unroll
  for (int n = 0; n < 16; ++n) acc[n] = f32x4{0.f, 0.f, 0.f, 0.f};

#pragma unroll 2
  for (int kk = 0; kk < 8; ++kk) {
#pragma unroll
    for (int n = 0; n < 16; ++n) {
      f16x8 bf = *(const f16x8*)(W16 + (n * 16 + c16) * DDIM + kk * 32 + g * 8);
      acc[n] = __builtin_amdgcn_mfma_f32_16x16x32_f16(qa[kk], bf, acc[n], 0, 0, 0);
    }
  }
#pragma unroll
  for (int n = 0; n < 16; ++n) {
    float bb = bias[n * 16 + c16];
#pragma unroll
    for (int r = 0; r < 4; ++r)
      qw16[(r0 + 4 * g + r) * DDIM + n * 16 + c16] = (_Float16)(acc[n][r] + bb);
  }
}

// ---------------- K2: fused attention (8 waves, TQ=128) ---------------------
// c_lds (q-major): byte = q*512 + d*2 ^ ((q&7)<<4); scores-A read b128:
//   off=(qs*16+c16)*512+kk*64+g*16 ^ ((c16&7)<<4).
// wbuf [64 o][128 q]: byte = o*256 + q*2 ^ ((o&7)<<4); write f16x4, read b128.
// DMA: linear LDS dest + inverse-swizzled global source (rule #21).
__global__ __launch_bounds__(512, 2) void attn_main(
    const _Float16* __restrict__ qw16,
    const _Float16* __restrict__ cT16,
    const _Float16* __restrict__ cD16,
    float* __restrict__ outp,
    float* __restrict__ wgt)
{
  __shared__ __align__(16) char smem[2][65536];  // c_lds double buffer (64KB)
  __shared__ __align__(16) char wbuf[16384];     // w tile [64 o][128 q] f16 swz
  __shared__ float redbuf[8][64];                // per-qs row sums
  char* obuf = &smem[0][0];                      // epilogue alias (64KB, dead)

  const int tid = threadIdx.x;
  const int wv  = tid >> 6;       // 0..7
  const int qs  = wv;             // scores q-frag 0..7
  const int dw  = wv >> 1;        // PV d-slice 0..3 (64 d)
  const int kh  = wv & 1;         // PV k-half 0..1 (64 q)
  const int ln  = tid & 63;
  const int g   = ln >> 4;
  const int c16 = ln & 15;

  // batch -> XCD-pair remap (context 2MB/batch stays L2-resident under lockstep)
  const int lin   = blockIdx.y * 64 + blockIdx.x;
  const int b     = (lin & 7) >> 1;
  const int otile = ((lin >> 3) << 1) | (lin & 1);
  const int o0    = otile * 64;
  const int bo    = b * LSEQ + o0;

  const _Float16* __restrict__ cbase = cT16 + (size_t)b * LSEQ * DDIM;
  const _Float16* __restrict__ cDb   = cD16 + (size_t)b * DDIM * LSEQ;

  // B-frags: o = of*16 + c16 (of 0..3 -> all 64 o), k = kk*32 + g*8..
  f16x8 qb[4][8];
#pragma unroll
  for (int of = 0; of < 4; ++of)
#pragma unroll
    for (int kk = 0; kk < 8; ++kk)
      qb[of][kk] = *(const f16x8*)(qw16 +
          ((size_t)(bo + of * 16 + c16) << 8) + kk * 32 + g * 8);

  auto issue_dma = [&](int t, int pp) {
#pragma unroll
    for (int i = 0; i < 8; ++i) {
      unsigned x  = (unsigned)tid * 16 + i * 8192;
      unsigned q  = x >> 9;
      unsigned db = (x & 511u) ^ ((q & 7u) << 4);
      gld16(cbase + ((size_t)(t * TQ + q) << 8) + (db >> 1), &smem[pp][x]);
    }
  };

  // scores: A from c_lds rows (q = qs*16 + c16), B = qb; D rows q=4g+r, col o
  auto scores = [&](const char* cl, f32x4 sa[4]) {
#pragma unroll
    for (int of = 0; of < 4; ++of) sa[of] = f32x4{0.f, 0.f, 0.f, 0.f};
#pragma unroll
    for (int kk = 0; kk < 8; ++kk) {
      unsigned off = (unsigned)((qs * 16 + c16) * 512 + kk * 64 + g * 16) ^
                     ((unsigned)(c16 & 7) << 4);
      f16x8 af = *(const f16x8*)(cl + off);
#pragma unroll
      for (int of = 0; of < 4; ++of)
        sa[of] = __builtin_amdgcn_mfma_f32_16x16x32_f16(af, qb[of][kk], sa[of], 0, 0, 0);
    }
  };

  // ---- phase A: staged scores, lsum += exp(s) ----
  float ls[4] = {0.f, 0.f, 0.f, 0.f};
  int p = 0;
  issue_dma(0, 0);
  for (int t = 0; t < LSEQ / TQ; ++t) {
    asm volatile("s_waitcnt vmcnt(0)" ::: "memory");
    __builtin_amdgcn_s_barrier();
    issue_dma(t < LSEQ / TQ - 1 ? t + 1 : 0, p ^ 1);  // t=31 stages B's tile 0
    __builtin_amdgcn_sched_barrier(0);

    f32x4 sa[4];
    scores(smem[p], sa);
#pragma unroll
    for (int of = 0; of < 4; ++of)
#pragma unroll
      for (int r = 0; r < 4; ++r) ls[of] += __expf(sa[of][r]);
    p ^= 1;
  }

  // reduce over g; redbuf[qs][o]; invl = 1/sum over the 8 q-frag waves
#pragma unroll
  for (int of = 0; of < 4; ++of) {
    ls[of] += __shfl_xor(ls[of], 16);
    ls[of] += __shfl_xor(ls[of], 32);
  }
  if (ln < 16) {
#pragma unroll
    for (int of = 0; of < 4; ++of) redbuf[qs][of * 16 + ln] = ls[of];
  }
  __syncthreads();
  float invl[4];
#pragma unroll
  for (int of = 0; of < 4; ++of) {
    float s = 0.f;
#pragma unroll
    for (int k = 0; k < 8; ++k) s += redbuf[k][of * 16 + c16];
    invl[of] = 1.0f / s;
  }

  // ---- phase B: staged scores (bit-identical), weights out, PV ----
  f32x4 oacc[4][4];
#pragma unroll
  for (int m = 0; m < 4; ++m)
#pragma unroll
    for (int nf = 0; nf < 4; ++nf) oacc[m][nf] = f32x4{0.f, 0.f, 0.f, 0.f};

  for (int t = 0; t < LSEQ / TQ; ++t) {
    const int q0 = t * TQ;
    if (t == 0) asm volatile("s_waitcnt vmcnt(0)" ::: "memory");
    else        asm volatile("s_waitcnt vmcnt(4)" ::: "memory");
    __builtin_amdgcn_s_barrier();
    __builtin_amdgcn_sched_barrier(0);

    if (t < LSEQ / TQ - 1) issue_dma(t + 1, p ^ 1);

    f32x4 sa[4];
    scores(smem[p], sa);

    // PV B-frags issued here: latency hides under exp/stores/barrier
    f16x8 bv[2][4];
#pragma unroll
    for (int ks = 0; ks < 2; ++ks)
#pragma unroll
      for (int nf = 0; nf < 4; ++nf)
        bv[ks][nf] = *(const f16x8*)(cDb +
            ((size_t)(dw * 64 + nf * 16 + c16) << 12) +
            q0 + kh * 64 + ks * 32 + g * 8);

    // weights: lane holds o = of*16+c16, q = q0+qs*16+4g+r (contig r)
#pragma unroll
    for (int of = 0; of < 4; ++of) {
      f32x4 wv4;
      f16x4 wh;
#pragma unroll
      for (int r = 0; r < 4; ++r) {
        float w = __expf(sa[of][r]) * invl[of];
        wv4[r] = w;
        wh[r]  = (_Float16)w;
      }
      int o = of * 16 + c16;
      *(f32x4*)(wgt + ((size_t)(bo + o) << 12) + q0 + qs * 16 + 4 * g) = wv4;
      unsigned wb = (unsigned)(o * 256 + (qs * 16 + 4 * g) * 2) ^
                    ((unsigned)(o & 7) << 4);
      *(f16x4*)(wbuf + wb) = wh;
    }
    asm volatile("s_waitcnt lgkmcnt(0)" ::: "memory");
    __builtin_amdgcn_s_barrier();
    __builtin_amdgcn_sched_barrier(0);

    // PV: A = wbuf rows (o), k-window kh*64+ks*32; B = bv; out d-slice dw
#pragma unroll
    for (int ks = 0; ks < 2; ++ks) {
#pragma unroll
      for (int m = 0; m < 4; ++m) {
        unsigned off = (unsigned)((m * 16 + c16) * 256 + kh * 128 + ks * 64 + g * 16) ^
                       ((unsigned)(c16 & 7) << 4);
        f16x8 wa = *(const f16x8*)(wbuf + off);
#pragma unroll
        for (int nf = 0; nf < 4; ++nf)
          oacc[m][nf] =
              __builtin_amdgcn_mfma_f32_16x16x32_f16(wa, bv[ks][nf], oacc[m][nf], 0, 0, 0);
      }
    }
    p ^= 1;
  }

  // ---- cross-kh reduction via obuf (smem dead), then store out
  __syncthreads();
  if (kh == 1) {
#pragma unroll
    for (int m = 0; m < 4; ++m)
#pragma unroll
      for (int nf = 0; nf < 4; ++nf)
        *(f32x4*)(obuf + dw * 16384 + (m * 4 + nf) * 1024 + ln * 16) = oacc[m][nf];
  }
  __syncthreads();
  if (kh == 0) {
#pragma unroll
    for (int m = 0; m < 4; ++m)
#pragma unroll
      for (int nf = 0; nf < 4; ++nf) {
        f32x4 o2 = *(const f32x4*)(obuf + dw * 16384 + (m * 4 + nf) * 1024 + ln * 16);
        f32x4 o  = oacc[m][nf] + o2;
#pragma unroll
        for (int r = 0; r < 4; ++r)
          outp[((size_t)(bo + m * 16 + 4 * g + r) << 8) + dw * 64 + nf * 16 + c16] = o[r];
      }
  }
}

extern "C" void kernel_launch(void* const* d_in, const int* in_sizes, int n_in,
                              void* d_out, int out_size, void* d_ws, size_t ws_size,
                              hipStream_t stream) {
  const float* query   = (const float*)d_in[0];
  const float* context = (const float*)d_in[1];
  const float* W_in    = (const float*)d_in[2];
  const float* b_in    = (const float*)d_in[3];

  float* outp = (float*)d_out;
  float* wgt  = outp + (size_t)BATCH * LSEQ * DDIM;  // outputs concat: out, weights

  const size_t NELEM = (size_t)BATCH * LSEQ * DDIM;  // 4,194,304
  _Float16* qT16 = (_Float16*)d_ws;
  _Float16* cT16 = qT16 + NELEM;
  _Float16* qw16 = cT16 + NELEM;
  _Float16* W16  = qw16 + NELEM;   // +65536 halfs
  _Float16* cD16 = W16 + 65536;    // context f16, [B][D][L]; total ws ~33.7 MB

  transpose_cast<<<dim3(LSEQ / 64, DDIM / 64, 2 * BATCH), 256, 0, stream>>>(
      query, context, qT16, cT16, cD16);
  wconv<<<(DDIM * DDIM) / 1024, 256, 0, stream>>>(W_in, W16);
  linear_q<<<(BATCH * LSEQ) / 64, 256, 0, stream>>>(qT16, W16, b_in, qw16);
  attn_main<<<dim3(64, BATCH), 512, 0, stream>>>(qw16, cT16, cD16, outp, wgt);
}

// Round 13
// 284.188 us; speedup vs baseline: 1.4782x; 1.4782x over previous
//
#include <hip/hip_runtime.h>

// Luong 'general' attention, B=4 D=256 L=4096.
// K0 transpose/cast q,c -> [B][L][D] f16 (+ fused cD16 [B][D][L] f16 cast);
// K0b W f32->f16 ; K1 linear qw=q@W^T+b.
// K2 attn_main: 256 blocks lockstep, 512 thr = 8 waves, launch_bounds(512,1)
//   (LDS 145KB pins 1 block/CU; bound=1 lets compiler use ~210 VGPR, NO spill —
//    r11/r12 both spilled and never tested the TQ=128 theory).
//   TQ=128, 32 iters/phase (r9==r10 at 3.7Kcy/iter => cost is per-iteration).
//   Scores: wave (w2,w1) owns q-frags {2w2,2w2+1} x o-frags {2w1,2w1+1}:
//     qb[2][8]=32v, sa[2][2], 2 A-reads/kk (2x redundancy).
//   PV: wave (dw=w2, kh=w1), oacc[4][4], bv[2][4] issued under exp/stores.
//   phase A: staged scores, lsum += exp(s); phase B: recompute (bit-identical),
//   w=exp(s)*invl -> f32x4 wgt + f16x4 wbuf; PV A=wbuf b128, B from L2-hot cD16.
// LDS: 2x64KB c_lds + 16KB wbuf + 1KB redbuf = 145 KB (obuf aliases smem[0]).

#define BATCH 4
#define DDIM  256
#define LSEQ  4096
#define TQ    128

typedef float    f32x4 __attribute__((ext_vector_type(4)));
typedef _Float16 f16x8 __attribute__((ext_vector_type(8)));
typedef _Float16 f16x4 __attribute__((ext_vector_type(4)));

__device__ __forceinline__ void gld16(const void* g, void* l) {
  __builtin_amdgcn_global_load_lds((const __attribute__((address_space(1))) void*)g,
                                   (__attribute__((address_space(3))) void*)l, 16, 0, 0);
}

// ---------------- K0: [B][D][L] f32 -> [B][L][D] f16 (+ cD16 for context) ---
__global__ __launch_bounds__(256) void transpose_cast(
    const float* __restrict__ q_in, const float* __restrict__ c_in,
    _Float16* __restrict__ q_out, _Float16* __restrict__ c_out,
    _Float16* __restrict__ cD16)
{
  __shared__ float tile[64][68];
  const int which = blockIdx.z >> 2;
  const int b     = blockIdx.z & 3;
  const float* __restrict__ src = which ? c_in : q_in;
  _Float16* __restrict__ dst    = which ? c_out : q_out;
  const int l0 = blockIdx.x * 64, d0 = blockIdx.y * 64;
  const int tid = threadIdx.x;
  const int tr = tid >> 4, tc = (tid & 15) << 2;
#pragma unroll
  for (int i = 0; i < 4; ++i) {
    int d = tr + i * 16;
    f32x4 v = *(const f32x4*)(src + ((size_t)b * DDIM + d0 + d) * LSEQ + l0 + tc);
    *(f32x4*)&tile[d][tc] = v;
    if (which) {
      f16x4 h;
      h[0] = (_Float16)v[0]; h[1] = (_Float16)v[1];
      h[2] = (_Float16)v[2]; h[3] = (_Float16)v[3];
      *(f16x4*)(cD16 + ((size_t)b * DDIM + d0 + d) * LSEQ + l0 + tc) = h;
    }
  }
  __syncthreads();
#pragma unroll
  for (int i = 0; i < 4; ++i) {
    int l = tr + i * 16;
    f16x4 h;
    h[0] = (_Float16)tile[tc + 0][l];
    h[1] = (_Float16)tile[tc + 1][l];
    h[2] = (_Float16)tile[tc + 2][l];
    h[3] = (_Float16)tile[tc + 3][l];
    *(f16x4*)(dst + ((size_t)b * LSEQ + l0 + l) * DDIM + d0 + tc) = h;
  }
}

// ---------------- K0b: W f32 -> f16 -----------------------------------------
__global__ __launch_bounds__(256) void wconv(const float* __restrict__ w,
                                             _Float16* __restrict__ w16) {
  int i = (blockIdx.x * 256 + threadIdx.x) * 4;
  f32x4 v = *(const f32x4*)(w + i);
  f16x4 h;
  h[0] = (_Float16)v[0]; h[1] = (_Float16)v[1];
  h[2] = (_Float16)v[2]; h[3] = (_Float16)v[3];
  *(f16x4*)(w16 + i) = h;
}

// ---------------- K1: qw16 = qT16 @ W^T + bias ------------------------------
__global__ __launch_bounds__(256) void linear_q(
    const _Float16* __restrict__ qT16, const _Float16* __restrict__ W16,
    const float* __restrict__ bias, _Float16* __restrict__ qw16)
{
  const int tid = threadIdx.x;
  const int wv = tid >> 6, ln = tid & 63, g = ln >> 4, c16 = ln & 15;
  const size_t r0 = (size_t)blockIdx.x * 64 + wv * 16;

  f16x8 qa[8];
  const _Float16* qrow = qT16 + (r0 + c16) * DDIM + g * 8;
#pragma unroll
  for (int kk = 0; kk < 8; ++kk) qa[kk] = *(const f16x8*)(qrow + kk * 32);

  f32x4 acc[16];
#pragma unroll
  for (int n = 0; n < 16; ++n) acc[n] = f32x4{0.f, 0.f, 0.f, 0.f};

#pragma unroll 2
  for (int kk = 0; kk < 8; ++kk) {
#pragma unroll
    for (int n = 0; n < 16; ++n) {
      f16x8 bf = *(const f16x8*)(W16 + (n * 16 + c16) * DDIM + kk * 32 + g * 8);
      acc[n] = __builtin_amdgcn_mfma_f32_16x16x32_f16(qa[kk], bf, acc[n], 0, 0, 0);
    }
  }
#pragma unroll
  for (int n = 0; n < 16; ++n) {
    float bb = bias[n * 16 + c16];
#pragma unroll
    for (int r = 0; r < 4; ++r)
      qw16[(r0 + 4 * g + r) * DDIM + n * 16 + c16] = (_Float16)(acc[n][r] + bb);
  }
}

// ---------------- K2: fused attention (8 waves, TQ=128) ---------------------
// c_lds (q-major): byte = q*512 + d*2 ^ ((q&7)<<4); scores-A read b128:
//   off=(qf*16+c16)*512+kk*64+g*16 ^ ((c16&7)<<4).
// wbuf [64 o][128 q]: byte = o*256 + q*2 ^ ((o&7)<<4); write f16x4, read b128.
// DMA: linear LDS dest + inverse-swizzled global source (rule #21).
__global__ __launch_bounds__(512, 1) void attn_main(
    const _Float16* __restrict__ qw16,
    const _Float16* __restrict__ cT16,
    const _Float16* __restrict__ cD16,
    float* __restrict__ outp,
    float* __restrict__ wgt)
{
  __shared__ __align__(16) char smem[2][65536];  // c_lds double buffer (64KB)
  __shared__ __align__(16) char wbuf[16384];     // w tile [64 o][128 q] f16 swz
  __shared__ float redbuf[4][64];                // per-w2 row sums
  char* obuf = &smem[0][0];                      // epilogue alias (64KB, dead)

  const int tid = threadIdx.x;
  const int wv  = tid >> 6;       // 0..7
  const int w2  = wv >> 1;        // 0..3: scores q-pair / PV d-slice
  const int w1  = wv & 1;         // 0..1: scores o-pair / PV k-half
  const int ln  = tid & 63;
  const int g   = ln >> 4;
  const int c16 = ln & 15;

  // batch -> XCD-pair remap (context 2MB/batch stays L2-resident under lockstep)
  const int lin   = blockIdx.y * 64 + blockIdx.x;
  const int b     = (lin & 7) >> 1;
  const int otile = ((lin >> 3) << 1) | (lin & 1);
  const int o0    = otile * 64;
  const int bo    = b * LSEQ + o0;

  const _Float16* __restrict__ cbase = cT16 + (size_t)b * LSEQ * DDIM;
  const _Float16* __restrict__ cDb   = cD16 + (size_t)b * DDIM * LSEQ;

  // B-frags: o = (w1*2+of)*16 + c16, k = kk*32 + g*8..
  f16x8 qb[2][8];
#pragma unroll
  for (int of = 0; of < 2; ++of)
#pragma unroll
    for (int kk = 0; kk < 8; ++kk)
      qb[of][kk] = *(const f16x8*)(qw16 +
          ((size_t)(bo + (w1 * 2 + of) * 16 + c16) << 8) + kk * 32 + g * 8);

  auto issue_dma = [&](int t, int pp) {
#pragma unroll
    for (int i = 0; i < 8; ++i) {
      unsigned x  = (unsigned)tid * 16 + i * 8192;
      unsigned q  = x >> 9;
      unsigned db = (x & 511u) ^ ((q & 7u) << 4);
      gld16(cbase + ((size_t)(t * TQ + q) << 8) + (db >> 1), &smem[pp][x]);
    }
  };

  // scores: A rows q = (w2*2+qf)*16 + c16; sa[qf][of]; D rows q=4g+r, col o
  auto scores = [&](const char* cl, f32x4 sa[2][2]) {
#pragma unroll
    for (int qf = 0; qf < 2; ++qf)
#pragma unroll
      for (int of = 0; of < 2; ++of) sa[qf][of] = f32x4{0.f, 0.f, 0.f, 0.f};
#pragma unroll
    for (int kk = 0; kk < 8; ++kk) {
#pragma unroll
      for (int qf = 0; qf < 2; ++qf) {
        unsigned off = (unsigned)(((w2 * 2 + qf) * 16 + c16) * 512 + kk * 64 + g * 16) ^
                       ((unsigned)(c16 & 7) << 4);
        f16x8 af = *(const f16x8*)(cl + off);
#pragma unroll
        for (int of = 0; of < 2; ++of)
          sa[qf][of] =
              __builtin_amdgcn_mfma_f32_16x16x32_f16(af, qb[of][kk], sa[qf][of], 0, 0, 0);
      }
    }
  };

  // ---- phase A: staged scores, lsum += exp(s) ----
  float ls[2] = {0.f, 0.f};
  int p = 0;
  issue_dma(0, 0);
  for (int t = 0; t < LSEQ / TQ; ++t) {
    asm volatile("s_waitcnt vmcnt(0)" ::: "memory");
    __builtin_amdgcn_s_barrier();
    issue_dma(t < LSEQ / TQ - 1 ? t + 1 : 0, p ^ 1);  // t=31 stages B's tile 0
    __builtin_amdgcn_sched_barrier(0);

    f32x4 sa[2][2];
    scores(smem[p], sa);
#pragma unroll
    for (int qf = 0; qf < 2; ++qf)
#pragma unroll
      for (int of = 0; of < 2; ++of)
#pragma unroll
        for (int r = 0; r < 4; ++r) ls[of] += __expf(sa[qf][of][r]);
    p ^= 1;
  }

  // reduce over g; redbuf[w2][o]; invl = 1/sum over the 4 w2 groups
#pragma unroll
  for (int of = 0; of < 2; ++of) {
    ls[of] += __shfl_xor(ls[of], 16);
    ls[of] += __shfl_xor(ls[of], 32);
  }
  if (ln < 16) {
#pragma unroll
    for (int of = 0; of < 2; ++of) redbuf[w2][w1 * 32 + of * 16 + ln] = ls[of];
  }
  __syncthreads();
  float invl[2];
#pragma unroll
  for (int of = 0; of < 2; ++of) {
    int o = w1 * 32 + of * 16 + c16;
    invl[of] = 1.0f / (redbuf[0][o] + redbuf[1][o] + redbuf[2][o] + redbuf[3][o]);
  }

  // ---- phase B: staged scores (bit-identical), weights out, PV ----
  f32x4 oacc[4][4];
#pragma unroll
  for (int m = 0; m < 4; ++m)
#pragma unroll
    for (int nf = 0; nf < 4; ++nf) oacc[m][nf] = f32x4{0.f, 0.f, 0.f, 0.f};

  for (int t = 0; t < LSEQ / TQ; ++t) {
    const int q0 = t * TQ;
    if (t == 0) asm volatile("s_waitcnt vmcnt(0)" ::: "memory");
    else        asm volatile("s_waitcnt vmcnt(4)" ::: "memory");
    __builtin_amdgcn_s_barrier();
    __builtin_amdgcn_sched_barrier(0);

    if (t < LSEQ / TQ - 1) issue_dma(t + 1, p ^ 1);

    f32x4 sa[2][2];
    scores(smem[p], sa);

    // PV B-frags issued here: latency hides under exp/stores/barrier
    f16x8 bv[2][4];
#pragma unroll
    for (int ks = 0; ks < 2; ++ks)
#pragma unroll
      for (int nf = 0; nf < 4; ++nf)
        bv[ks][nf] = *(const f16x8*)(cDb +
            ((size_t)(w2 * 64 + nf * 16 + c16) << 12) +
            q0 + w1 * 64 + ks * 32 + g * 8);

    // weights: lane holds o = (w1*2+of)*16+c16, q = q0+(w2*2+qf)*16+4g+r
#pragma unroll
    for (int qf = 0; qf < 2; ++qf)
#pragma unroll
      for (int of = 0; of < 2; ++of) {
        f32x4 wv4;
        f16x4 wh;
#pragma unroll
        for (int r = 0; r < 4; ++r) {
          float w = __expf(sa[qf][of][r]) * invl[of];
          wv4[r] = w;
          wh[r]  = (_Float16)w;
        }
        int o  = (w1 * 2 + of) * 16 + c16;
        int ql = (w2 * 2 + qf) * 16 + 4 * g;
        *(f32x4*)(wgt + ((size_t)(bo + o) << 12) + q0 + ql) = wv4;
        unsigned wb = (unsigned)(o * 256 + ql * 2) ^ ((unsigned)(o & 7) << 4);
        *(f16x4*)(wbuf + wb) = wh;
      }
    asm volatile("s_waitcnt lgkmcnt(0)" ::: "memory");
    __builtin_amdgcn_s_barrier();
    __builtin_amdgcn_sched_barrier(0);

    // PV: A = wbuf rows (o), k-window w1*64+ks*32; B = bv; out d-slice w2
#pragma unroll
    for (int ks = 0; ks < 2; ++ks) {
#pragma unroll
      for (int m = 0; m < 4; ++m) {
        unsigned off = (unsigned)((m * 16 + c16) * 256 + w1 * 128 + ks * 64 + g * 16) ^
                       ((unsigned)(c16 & 7) << 4);
        f16x8 wa = *(const f16x8*)(wbuf + off);
#pragma unroll
        for (int nf = 0; nf < 4; ++nf)
          oacc[m][nf] =
              __builtin_amdgcn_mfma_f32_16x16x32_f16(wa, bv[ks][nf], oacc[m][nf], 0, 0, 0);
      }
    }
    p ^= 1;
  }

  // ---- cross-w1 reduction via obuf (smem dead), then store out
  __syncthreads();
  if (w1 == 1) {
#pragma unroll
    for (int m = 0; m < 4; ++m)
#pragma unroll
      for (int nf = 0; nf < 4; ++nf)
        *(f32x4*)(obuf + w2 * 16384 + (m * 4 + nf) * 1024 + ln * 16) = oacc[m][nf];
  }
  __syncthreads();
  if (w1 == 0) {
#pragma unroll
    for (int m = 0; m < 4; ++m)
#pragma unroll
      for (int nf = 0; nf < 4; ++nf) {
        f32x4 o2 = *(const f32x4*)(obuf + w2 * 16384 + (m * 4 + nf) * 1024 + ln * 16);
        f32x4 o  = oacc[m][nf] + o2;
#pragma unroll
        for (int r = 0; r < 4; ++r)
          outp[((size_t)(bo + m * 16 + 4 * g + r) << 8) + w2 * 64 + nf * 16 + c16] = o[r];
      }
  }
}

extern "C" void kernel_launch(void* const* d_in, const int* in_sizes, int n_in,
                              void* d_out, int out_size, void* d_ws, size_t ws_size,
                              hipStream_t stream) {
  const float* query   = (const float*)d_in[0];
  const float* context = (const float*)d_in[1];
  const float* W_in    = (const float*)d_in[2];
  const float* b_in    = (const float*)d_in[3];

  float* outp = (float*)d_out;
  float* wgt  = outp + (size_t)BATCH * LSEQ * DDIM;  // outputs concat: out, weights

  const size_t NELEM = (size_t)BATCH * LSEQ * DDIM;  // 4,194,304
  _Float16* qT16 = (_Float16*)d_ws;
  _Float16* cT16 = qT16 + NELEM;
  _Float16* qw16 = cT16 + NELEM;
  _Float16* W16  = qw16 + NELEM;   // +65536 halfs
  _Float16* cD16 = W16 + 65536;    // context f16, [B][D][L]; total ws ~33.7 MB

  transpose_cast<<<dim3(LSEQ / 64, DDIM / 64, 2 * BATCH), 256, 0, stream>>>(
      query, context, qT16, cT16, cD16);
  wconv<<<(DDIM * DDIM) / 1024, 256, 0, stream>>>(W_in, W16);
  linear_q<<<(BATCH * LSEQ) / 64, 256, 0, stream>>>(qT16, W16, b_in, qw16);
  attn_main<<<dim3(64, BATCH), 512, 0, stream>>>(qw16, cT16, cD16, outp, wgt);
}